// Round 1
// baseline (109.856 us; speedup 1.0000x reference)
//
#include <hip/hip_runtime.h>
#include <math.h>

#define N_HIT  50000
#define N_TRUE 512
#define N_EDGE 40000
#define Q_MIN  0.5f

#define MASK_WORDS_PER_HIT (N_TRUE / 32)   // 16
#define KSPLIT 2
#define KCH (N_TRUE / KSPLIT)              // 256
#define HB ((N_HIT + 255) / 256)           // 196 hit-blocks

// ws layout (4-byte words):
// [0,512)     f_centers bits (uint; positive-float bits order == float order)
// [512,1024)  centers (int)
// [1024,1536) qc (float)
// [1536..)    accum: [0]=sum_fc [1]=sum_f_bkg [2]=n_bkg(uint) [3]=v_acc
// [2048, 2048 + N_HIT*16) membership bitmask

__global__ void k_edge_max(const float* __restrict__ f,
                           const int* __restrict__ e_h, const int* __restrict__ e_p,
                           unsigned* __restrict__ fc_bits) {
    int e = blockIdx.x * blockDim.x + threadIdx.x;
    if (e < N_EDGE) {
        float fe = f[e_h[e]];
        atomicMax(&fc_bits[e_p[e]], __float_as_uint(fe));
    }
}

__global__ void k_edge_argmax_mask(const float* __restrict__ f,
                                   const int* __restrict__ e_h, const int* __restrict__ e_p,
                                   const unsigned* __restrict__ fc_bits,
                                   int* __restrict__ centers, unsigned* __restrict__ mask) {
    int e = blockIdx.x * blockDim.x + threadIdx.x;
    if (e < N_EDGE) {
        int h = e_h[e], p = e_p[e];
        if (__float_as_uint(f[h]) == fc_bits[p])
            atomicMax(&centers[p], h);
        atomicOr(&mask[(size_t)h * MASK_WORDS_PER_HIT + (p >> 5)], 1u << (p & 31));
    }
}

__global__ void k_scalars(const float* __restrict__ f, const int* __restrict__ y,
                          const unsigned* __restrict__ fc_bits, const int* __restrict__ centers,
                          float* __restrict__ qc, float* __restrict__ accum) {
    int i = blockIdx.x * blockDim.x + threadIdx.x;
    if (i < N_TRUE) {
        float fc = f[centers[i]];
        float a  = atanhf(fc);
        qc[i] = fmaf(a, a, Q_MIN);
        atomicAdd(&accum[0], __uint_as_float(fc_bits[i]));  // f_centers value
    }
    if (i < N_HIT) {
        if (y[i] == -1) {
            atomicAdd(&accum[1], f[i]);
            atomicAdd((unsigned*)&accum[2], 1u);
        }
    }
}

__global__ __launch_bounds__(256) void k_main(const float* __restrict__ x,
                                              const float* __restrict__ f,
                                              const int* __restrict__ centers,
                                              const float* __restrict__ qc,
                                              const unsigned* __restrict__ mask,
                                              float* __restrict__ accum) {
    __shared__ float4 xcs[KCH][2];
    __shared__ float  qcs[KCH];
    __shared__ float  wsum[4];

    int hb = blockIdx.x % HB;          // hit-block
    int kb = blockIdx.x / HB;          // k-chunk (0..KSPLIT-1)
    int k0 = kb * KCH;
    int t  = threadIdx.x;

    {   // stage this k-chunk's center coords + weights (KCH == blockDim)
        int c = centers[k0 + t];
        const float4* xp = (const float4*)(x + (size_t)c * 8);
        xcs[t][0] = xp[0];
        xcs[t][1] = xp[1];
        qcs[t]    = qc[k0 + t];
    }
    __syncthreads();

    int   i    = hb * 256 + t;
    float vout = 0.0f;
    if (i < N_HIT) {
        const float4* xp = (const float4*)(x + (size_t)i * 8);
        float4 a0 = xp[0], a1 = xp[1];

        const uint4* mp = (const uint4*)(mask + (size_t)i * MASK_WORDS_PER_HIT + kb * (KCH / 32));
        uint4 m0 = mp[0], m1 = mp[1];
        unsigned mw[8] = {m0.x, m0.y, m0.z, m0.w, m1.x, m1.y, m1.z, m1.w};

        float fi = f[i];
        float at = atanhf(fi);
        float qi = fmaf(at, at, Q_MIN);

        float acc = 0.0f;
#pragma unroll 8
        for (int k = 0; k < KCH; k++) {
            float4 c0 = xcs[k][0], c1 = xcs[k][1];
            float d, dist;
            d = a0.x - c0.x; dist = d * d;
            d = a0.y - c0.y; dist = fmaf(d, d, dist);
            d = a0.z - c0.z; dist = fmaf(d, d, dist);
            d = a0.w - c0.w; dist = fmaf(d, d, dist);
            d = a1.x - c1.x; dist = fmaf(d, d, dist);
            d = a1.y - c1.y; dist = fmaf(d, d, dist);
            d = a1.z - c1.z; dist = fmaf(d, d, dist);
            d = a1.w - c1.w; dist = fmaf(d, d, dist);
            float rep = fmaxf(1.0f - dist, 0.0f);
            bool  mem = (mw[k >> 5] >> (k & 31)) & 1u;
            float sel = mem ? dist : rep;
            acc = fmaf(sel, qcs[k], acc);
        }
        vout = acc * qi;
    }

    // block reduction: wave64 shuffle, then cross-wave via LDS
    for (int off = 32; off > 0; off >>= 1)
        vout += __shfl_down(vout, off, 64);
    if ((t & 63) == 0) wsum[t >> 6] = vout;
    __syncthreads();
    if (t == 0)
        atomicAdd(&accum[3], wsum[0] + wsum[1] + wsum[2] + wsum[3]);
}

__global__ void k_finalize(const float* __restrict__ accum, float* __restrict__ out) {
    if (threadIdx.x == 0 && blockIdx.x == 0) {
        float b1 = 1.0f - accum[0] / (float)N_TRUE;
        unsigned nb = ((const unsigned*)accum)[2];
        float b2 = accum[1] / (float)nb;   // S_B = 1.0
        out[0] = b1 + b2;
        out[1] = accum[3] / (float)N_HIT;
    }
}

extern "C" void kernel_launch(void* const* d_in, const int* in_sizes, int n_in,
                              void* d_out, int out_size, void* d_ws, size_t ws_size,
                              hipStream_t stream) {
    const float* x   = (const float*)d_in[0];
    const float* f   = (const float*)d_in[1];
    const int*   y   = (const int*)d_in[2];
    const int*   e_h = (const int*)d_in[3];
    const int*   e_p = (const int*)d_in[4];
    float* out = (float*)d_out;

    unsigned* ws      = (unsigned*)d_ws;
    unsigned* fc_bits = ws;
    int*      centers = (int*)(ws + 512);
    float*    qc      = (float*)(ws + 1024);
    float*    accum   = (float*)(ws + 1536);
    unsigned* mask    = ws + 2048;

    size_t total_bytes = (size_t)(2048 + (size_t)N_HIT * MASK_WORDS_PER_HIT) * 4;
    hipMemsetAsync(d_ws, 0, total_bytes, stream);

    k_edge_max<<<(N_EDGE + 255) / 256, 256, 0, stream>>>(f, e_h, e_p, fc_bits);
    k_edge_argmax_mask<<<(N_EDGE + 255) / 256, 256, 0, stream>>>(f, e_h, e_p, fc_bits, centers, mask);
    k_scalars<<<(N_HIT + 255) / 256, 256, 0, stream>>>(f, y, fc_bits, centers, qc, accum);
    k_main<<<HB * KSPLIT, 256, 0, stream>>>(x, f, centers, qc, mask, accum);
    k_finalize<<<1, 64, 0, stream>>>(accum, out);
}